// Round 12
// baseline (185.609 us; speedup 1.0000x reference)
//
#include <hip/hip_runtime.h>
#include <hip/hip_fp16.h>
#include <math.h>

#define N_PTS  131072
#define K_DIM  16
#define D_BINS 1024
// f16 screen commit margin: 2*(f16 quant 4.9e-4 + flush 4.8e-4 + accum 1e-5
//                              + pack quantize 4.88e-4) ~ 2.9e-3; use 3.2e-3
#define MARGIN_P 3.2e-3f

typedef _Float16 f16x8 __attribute__((ext_vector_type(8)));
typedef float    f32x4 __attribute__((ext_vector_type(4)));

// ws layout (bytes):
// [0,4) wl_count | [64,+64K) bnT rows | [65600,+32K) Bh (f16 frags)
// | [98368,+512K) worklist (all 131072 points fit)
#define WS_OFF_BN  64
#define WS_OFF_BH  65600
#define WS_OFF_WL  98368
#define WS_NEED    (WS_OFF_WL + 4 * N_PTS)

// np-exact normalization over K (sequential ascending k, no fma).
__device__ __forceinline__ void norm_np(const float* __restrict__ p,
                                        int stride, int n, float* __restrict__ a) {
#pragma clang fp contract(off)
    float v[K_DIM];
#pragma unroll
    for (int k = 0; k < K_DIM; ++k) v[k] = p[(size_t)k * stride + n];
    float s = v[0];
#pragma unroll
    for (int k = 1; k < K_DIM; ++k) s = s + v[k];
    const float mean = s / 16.0f;
    float sq[K_DIM];
#pragma unroll
    for (int k = 0; k < K_DIM; ++k) { a[k] = v[k] - mean; sq[k] = a[k] * a[k]; }
    float ss = sq[0];
#pragma unroll
    for (int k = 1; k < K_DIM; ++k) ss = ss + sq[k];
    const float denom = sqrtf(ss) + 1e-10f;
#pragma unroll
    for (int k = 0; k < K_DIM; ++k) a[k] = a[k] / denom;
}

__device__ __forceinline__ unsigned short f16_bits(float f) {
    const _Float16 h = (_Float16)f;   // v_cvt_f16_f32, RNE
    return __builtin_bit_cast(unsigned short, h);
}

// Kernel 1: np-exact cmat normalize -> bnT rows + f16 MFMA B-fragments
// (fragment layout identical to R8-R11's proven B1); zero wl counter.
__global__ __launch_bounds__(256) void prep_b(
    const float* __restrict__ cmat, float* __restrict__ bnT,
    unsigned short* __restrict__ Bh, int* __restrict__ wl_count) {
#pragma clang fp contract(off)
    if (blockIdx.x == 0 && threadIdx.x == 0) *wl_count = 0;
    const int d = blockIdx.x * 256 + threadIdx.x;   // grid = 4 * 256
    if (d >= D_BINS) return;

    float t[K_DIM];
    norm_np(cmat, D_BINS, d, t);

    const int tile = d >> 4, n = d & 15;
#pragma unroll
    for (int k = 0; k < K_DIM; ++k) {
        bnT[d * K_DIM + k] = t[k];
        const int idx = tile * 256 + ((k >> 3) * 16 + n) * 8 + (k & 7);
        Bh[idx] = f16_bits(t[k]);
    }
}

// Kernel 2: single-MFMA f16 screen. Block = 512 thr (8 waves), LDS = Bh
// (32 KB) -> 4 blocks/CU. Wave owns 16 points. A = [f16(a)|0] (upper K-half
// zero), B mirrored across lane halves -> one mfma_f32_16x16x32_f16 per
// 16-bin tile: acc = a*b + 2.0 (positive -> uint-sortable).
// Top-2 tracked as packed uint (score&~0x7FF)|(2047-d): uint max == higher
// score, ties -> lower d (np first-max-wins).
__global__ __launch_bounds__(512, 8) void mfma_screen(
    const float* __restrict__ x, const uint4* __restrict__ Bh,
    int* __restrict__ out, int* __restrict__ wl, int* __restrict__ wl_count) {
#pragma clang fp contract(off)
    __shared__ uint4 ldsB[2048];     // 32 KB

    {
#pragma unroll
        for (int j = 0; j < 4; ++j)
            ldsB[threadIdx.x + j * 512] = Bh[threadIdx.x + j * 512];
    }

    const int lane = threadIdx.x & 63;
    const int wv   = threadIdx.x >> 6;              // 0..7
    const int W    = blockIdx.x * 8 + wv;           // grid = 1024 * 512
    const int P    = W * 16;
    const int m    = lane & 15;                     // bin column within tile
    const int q    = lane >> 4;                     // quad

    // A fragment: kp=(lane>>4)*8+j; kp<16 -> f16(a[kp]), kp>=16 -> 0.
    f16x8 A;
    {
        float a[K_DIM];
        norm_np(x, N_PTS, P + m, a);
        unsigned short els[8];
#pragma unroll
        for (int j = 0; j < 8; ++j) {
            const int k = (q & 1) * 8 + j;
            els[j] = (q < 2) ? f16_bits(a[k]) : (unsigned short)0;
        }
        __builtin_memcpy(&A, els, 16);
    }

    __syncthreads();

    // B frags from LDS; lanes L and L+32 read the same address (broadcast);
    // the upper-K mirror is multiplied by A's zero half -> exact.
    const uint4* bp = ldsB + (lane & 31);

    unsigned ub1[4], ub2[4];
#pragma unroll
    for (int r = 0; r < 4; ++r) { ub1[r] = 0u; ub2[r] = 0u; }

    const unsigned mask  = 0xFFFFF800u;
    const unsigned dbase = 2047u - (unsigned)m;

#pragma unroll 4
    for (int i = 0; i < 64; ++i) {
        const uint4 w1 = bp[i * 32];
        const f16x8 bf = __builtin_bit_cast(f16x8, w1);

        const f32x4 acc = __builtin_amdgcn_mfma_f32_16x16x32_f16(
            A, bf, (f32x4){2.f, 2.f, 2.f, 2.f}, 0, 0, 0);

        const unsigned dcomp = dbase - (unsigned)(i * 16);
#pragma unroll
        for (int r = 0; r < 4; ++r) {
            const unsigned u = (__float_as_uint(acc[r]) & mask) | dcomp;
            const unsigned nx = max(ub1[r], u);
            ub2[r] = max(ub2[r], min(ub1[r], u));
            ub1[r] = nx;
        }
    }

    // merge top-2 across the 16 bin-columns (m) of each quad group
#pragma unroll
    for (int r = 0; r < 4; ++r) {
        unsigned u1 = ub1[r], u2 = ub2[r];
#pragma unroll
        for (int s = 1; s <= 8; s <<= 1) {
            const unsigned o1 = (unsigned)__shfl_xor((int)u1, s, 16);
            const unsigned o2 = (unsigned)__shfl_xor((int)u2, s, 16);
            const unsigned n1 = max(u1, o1);
            u2 = max(min(u1, o1), max(u2, o2));
            u1 = n1;
        }
        if (m == 0) {
            const int p  = P + q * 4 + r;
            const float s1 = __uint_as_float(u1 & mask);
            const float s2 = __uint_as_float(u2 & mask);
            if (s1 - s2 > MARGIN_P) {
                out[p] = 2047 - (int)(u1 & 2047u);
            } else {
                const int pos = atomicAdd(wl_count, 1);
                wl[pos] = p;
            }
        }
    }
}

// Kernel 3: np-exact rescan, one wave per worklisted point (proven R7-R11).
__global__ __launch_bounds__(256) void ncc_exact_refine(
    const float* __restrict__ x, const float* __restrict__ bnT,
    int* __restrict__ out, const int* __restrict__ wl,
    const int* __restrict__ wl_count) {
#pragma clang fp contract(off)
    const int count  = *wl_count;
    const int lane   = threadIdx.x & 63;
    const int wave   = (blockIdx.x * 256 + threadIdx.x) >> 6;
    const int nwaves = (gridDim.x * 256) >> 6;

    for (int i = wave; i < count; i += nwaves) {
        const int n = wl[i];
        float a[K_DIM];
        norm_np(x, N_PTS, n, a);

        float best = -3.402823466e38f;
        int   idx  = 0x7fffffff;
        const float4* b4 = (const float4*)bnT;
        for (int t = 0; t < 16; ++t) {
            const int d = t * 64 + lane;
            const float4 q0 = b4[d * 4 + 0];
            const float4 q1 = b4[d * 4 + 1];
            const float4 q2 = b4[d * 4 + 2];
            const float4 q3 = b4[d * 4 + 3];
            float sc;
            sc = a[0] * q0.x;
            sc = sc + a[1]  * q0.y; sc = sc + a[2]  * q0.z; sc = sc + a[3]  * q0.w;
            sc = sc + a[4]  * q1.x; sc = sc + a[5]  * q1.y; sc = sc + a[6]  * q1.z;
            sc = sc + a[7]  * q1.w; sc = sc + a[8]  * q2.x; sc = sc + a[9]  * q2.y;
            sc = sc + a[10] * q2.z; sc = sc + a[11] * q2.w; sc = sc + a[12] * q3.x;
            sc = sc + a[13] * q3.y; sc = sc + a[14] * q3.z; sc = sc + a[15] * q3.w;
            if (sc > best) { best = sc; idx = d; }
        }
#pragma unroll
        for (int mk = 1; mk <= 32; mk <<= 1) {
            const float ob = __shfl_xor(best, mk);
            const int   oi = __shfl_xor(idx,  mk);
            if (ob > best || (ob == best && oi < idx)) { best = ob; idx = oi; }
        }
        if (lane == 0) out[n] = idx;
    }
}

// Fallback (small ws): proven-exact full scan (R4).
__global__ __launch_bounds__(256) void ncc_argmax_np32(
    const float* __restrict__ x, const float* __restrict__ bnT,
    int* __restrict__ out) {
#pragma clang fp contract(off)
    const int n = blockIdx.x * 256 + threadIdx.x;
    float a[K_DIM];
    norm_np(x, N_PTS, n, a);

    float best = -3.402823466e38f;
    int   idx  = 0;
    const float4* b4 = (const float4*)bnT;
#pragma unroll 2
    for (int d = 0; d < D_BINS; ++d) {
        const float4 q0 = b4[d * 4 + 0];
        const float4 q1 = b4[d * 4 + 1];
        const float4 q2 = b4[d * 4 + 2];
        const float4 q3 = b4[d * 4 + 3];
        float sc;
        sc = a[0] * q0.x;
        sc = sc + a[1]  * q0.y; sc = sc + a[2]  * q0.z; sc = sc + a[3]  * q0.w;
        sc = sc + a[4]  * q1.x; sc = sc + a[5]  * q1.y; sc = sc + a[6]  * q1.z;
        sc = sc + a[7]  * q1.w; sc = sc + a[8]  * q2.x; sc = sc + a[9]  * q2.y;
        sc = sc + a[10] * q2.z; sc = sc + a[11] * q2.w; sc = sc + a[12] * q3.x;
        sc = sc + a[13] * q3.y; sc = sc + a[14] * q3.z; sc = sc + a[15] * q3.w;
        if (sc > best) { best = sc; idx = d; }
    }
    out[n] = idx;
}

__global__ __launch_bounds__(256) void normalize_rows_only(
    const float* __restrict__ cmat, float* __restrict__ bnT) {
#pragma clang fp contract(off)
    const int d = blockIdx.x * 256 + threadIdx.x;
    if (d >= D_BINS) return;
    float t[K_DIM];
    norm_np(cmat, D_BINS, d, t);
#pragma unroll
    for (int k = 0; k < K_DIM; ++k) bnT[d * K_DIM + k] = t[k];
}

extern "C" void kernel_launch(void* const* d_in, const int* in_sizes, int n_in,
                              void* d_out, int out_size, void* d_ws, size_t ws_size,
                              hipStream_t stream) {
    const float* x    = (const float*)d_in[0];   // [1, 16, 131072] fp32
    const float* cmat = (const float*)d_in[1];   // [16, 1024] fp32
    int* out = (int*)d_out;                      // [1, 131072] int32
    char* ws = (char*)d_ws;

    if (ws_size >= (size_t)WS_NEED) {
        int*            wl_count = (int*)ws;
        float*          bnT      = (float*)(ws + WS_OFF_BN);
        unsigned short* Bh       = (unsigned short*)(ws + WS_OFF_BH);
        int*            wl       = (int*)(ws + WS_OFF_WL);

        prep_b<<<4, 256, 0, stream>>>(cmat, bnT, Bh, wl_count);
        mfma_screen<<<1024, 512, 0, stream>>>(
            x, (const uint4*)(ws + WS_OFF_BH), out, wl, wl_count);
        ncc_exact_refine<<<1024, 256, 0, stream>>>(x, bnT, out, wl, wl_count);
    } else {
        float* bnT = (float*)(ws + WS_OFF_BN);
        normalize_rows_only<<<4, 256, 0, stream>>>(cmat, bnT);
        ncc_argmax_np32<<<512, 256, 0, stream>>>(x, bnT, out);
    }
}

// Round 13
// 114.135 us; speedup vs baseline: 1.6262x; 1.6262x over previous
//
#include <hip/hip_runtime.h>
#include <hip/hip_bf16.h>
#include <math.h>

#define N_PTS  131072
#define K_DIM  16
#define D_BINS 1024
// packed-screen commit margin: quantize (2^-11=4.88e-4) + screen err (~5e-5)
#define MARGIN_P 6e-4f

typedef short bf16x8 __attribute__((ext_vector_type(8)));
typedef float f32x4  __attribute__((ext_vector_type(4)));

// ws layout (bytes):
// [0,4K) counts[1024] | [4K,+64K) bnT rows | [69632,+32K) B1 | [102400,+32K) B2
// | [135168,+16) zero uint4 (== B2 entry 2048) | [135184,+256K) wl segments
//   (1024 blocks x 64 ints)                       total 397,328
#define WS_OFF_CNT 0
#define WS_OFF_BN  4096
#define WS_OFF_B1  69632
#define WS_OFF_B2  102400
#define WS_OFF_Z   135168
#define WS_OFF_WL  135184
#define WS_NEED    397328

// np-exact normalization over K (sequential ascending k, no fma).
__device__ __forceinline__ void norm_np(const float* __restrict__ p,
                                        int stride, int n, float* __restrict__ a) {
#pragma clang fp contract(off)
    float v[K_DIM];
#pragma unroll
    for (int k = 0; k < K_DIM; ++k) v[k] = p[(size_t)k * stride + n];
    float s = v[0];
#pragma unroll
    for (int k = 1; k < K_DIM; ++k) s = s + v[k];
    const float mean = s / 16.0f;
    float sq[K_DIM];
#pragma unroll
    for (int k = 0; k < K_DIM; ++k) { a[k] = v[k] - mean; sq[k] = a[k] * a[k]; }
    float ss = sq[0];
#pragma unroll
    for (int k = 1; k < K_DIM; ++k) ss = ss + sq[k];
    const float denom = sqrtf(ss) + 1e-10f;
#pragma unroll
    for (int k = 0; k < K_DIM; ++k) a[k] = a[k] / denom;
}

__device__ __forceinline__ unsigned short bf16_bits(float f) {
    __hip_bfloat16 h = __float2bfloat16(f);   // RNE
    unsigned short u;
    __builtin_memcpy(&u, &h, 2);
    return u;
}
__device__ __forceinline__ float bf16_val(float f) {
    return __bfloat162float(__float2bfloat16(f));
}

// Kernel 1: np-exact cmat normalize -> bnT rows + hi/lo MFMA B-fragments
// (layout proven R8-R11); zero uint4 at B2 entry 2048.
__global__ __launch_bounds__(256) void prep_b(
    const float* __restrict__ cmat, float* __restrict__ bnT,
    unsigned short* __restrict__ B1, unsigned short* __restrict__ B2,
    unsigned short* __restrict__ zblk) {
#pragma clang fp contract(off)
    if (blockIdx.x == 0 && threadIdx.x < 8) zblk[threadIdx.x] = 0;
    const int d = blockIdx.x * 256 + threadIdx.x;   // grid = 4 * 256
    if (d >= D_BINS) return;

    float t[K_DIM];
    norm_np(cmat, D_BINS, d, t);

    const int tile = d >> 4, n = d & 15;
#pragma unroll
    for (int k = 0; k < K_DIM; ++k) {
        bnT[d * K_DIM + k] = t[k];
        const float hi_f = bf16_val(t[k]);
        const int idx = tile * 256 + ((k >> 3) * 16 + n) * 8 + (k & 7);
        B1[idx] = bf16_bits(t[k]);
        B2[idx] = bf16_bits(t[k] - hi_f);
    }
}

// Kernel 2: MFMA screen (R11 hot loop verbatim: bf16 hi/lo, 2 MFMA, typed
// uint4 loads; LDS = B1 32 KB -> 4 blocks/CU; B2 from global, lanes>=32 ->
// zero entry 2048). NEW: zero device-scope atomics. Flagged points collect
// via LDS atomics into a per-block list; one coalesced write into a private
// 64-entry segment + counts[block]. count>64 => sentinel: refine rescans
// the whole block's 128 points (deterministic, np-exact either way).
__global__ __launch_bounds__(512, 8) void mfma_screen(
    const float* __restrict__ x, const uint4* __restrict__ B1,
    const uint4* __restrict__ B2,
    int* __restrict__ out, int* __restrict__ wl, int* __restrict__ counts) {
#pragma clang fp contract(off)
    __shared__ uint4 ldsB[2048];     // B1: 32 KB
    __shared__ int s_cnt;
    __shared__ int s_list[64];

    if (threadIdx.x == 0) s_cnt = 0;
    {
#pragma unroll
        for (int j = 0; j < 4; ++j)
            ldsB[threadIdx.x + j * 512] = B1[threadIdx.x + j * 512];
    }

    const int lane = threadIdx.x & 63;
    const int wv   = threadIdx.x >> 6;              // 0..7
    const int W    = blockIdx.x * 8 + wv;           // grid = 1024 * 512
    const int P    = W * 16;
    const int m    = lane & 15;                     // bin column within tile
    const int q    = lane >> 4;                     // quad

    // A fragment: kp=(lane>>4)*8+j; kp<16 -> hi, kp>=16 -> lo.
    bf16x8 A;
    {
        float a[K_DIM];
        norm_np(x, N_PTS, P + m, a);
        unsigned short els[8];
#pragma unroll
        for (int j = 0; j < 8; ++j) {
            const int k = (q & 1) * 8 + j;
            if (q < 2) els[j] = bf16_bits(a[k]);
            else       els[j] = bf16_bits(a[k] - bf16_val(a[k]));
        }
        __builtin_memcpy(&A, els, 16);
    }

    __syncthreads();

    // B1 from LDS (lanes L, L+32 same address -> broadcast). B2 from global;
    // lanes>=32 index the zero entry at 2048 (stride 0).
    const uint4* b1p = ldsB + (lane & 31);
    const int b2base = (lane < 32) ? lane : 2048;
    const int b2step = (lane < 32) ? 32 : 0;

    unsigned ub1[4], ub2[4];
#pragma unroll
    for (int r = 0; r < 4; ++r) { ub1[r] = 0u; ub2[r] = 0u; }

    const unsigned mask  = 0xFFFFF800u;
    const unsigned dbase = 2047u - (unsigned)m;

#pragma unroll 4
    for (int i = 0; i < 64; ++i) {
        const uint4 w1 = b1p[i * 32];
        const uint4 w2 = B2[b2base + i * b2step];
        const bf16x8 bf1 = __builtin_bit_cast(bf16x8, w1);
        const bf16x8 bf2 = __builtin_bit_cast(bf16x8, w2);

        f32x4 acc = __builtin_amdgcn_mfma_f32_16x16x32_bf16(
            A, bf1, (f32x4){2.f, 2.f, 2.f, 2.f}, 0, 0, 0);
        acc = __builtin_amdgcn_mfma_f32_16x16x32_bf16(A, bf2, acc, 0, 0, 0);

        const unsigned dcomp = dbase - (unsigned)(i * 16);
#pragma unroll
        for (int r = 0; r < 4; ++r) {
            const unsigned u = (__float_as_uint(acc[r]) & mask) | dcomp;
            const unsigned nx = max(ub1[r], u);
            ub2[r] = max(ub2[r], min(ub1[r], u));
            ub1[r] = nx;
        }
    }

    // merge top-2 across the 16 bin-columns (m) of each quad group
#pragma unroll
    for (int r = 0; r < 4; ++r) {
        unsigned u1 = ub1[r], u2 = ub2[r];
#pragma unroll
        for (int s = 1; s <= 8; s <<= 1) {
            const unsigned o1 = (unsigned)__shfl_xor((int)u1, s, 16);
            const unsigned o2 = (unsigned)__shfl_xor((int)u2, s, 16);
            const unsigned n1 = max(u1, o1);
            u2 = max(min(u1, o1), max(u2, o2));
            u1 = n1;
        }
        if (m == 0) {
            const int p  = P + q * 4 + r;
            const float s1 = __uint_as_float(u1 & mask);
            const float s2 = __uint_as_float(u2 & mask);
            if (s1 - s2 > MARGIN_P) {
                out[p] = 2047 - (int)(u1 & 2047u);
            } else {
                const int pos = atomicAdd(&s_cnt, 1);   // LDS atomic: cheap
                if (pos < 64) s_list[pos] = p;
            }
        }
    }

    __syncthreads();
    const int c = s_cnt;
    if (threadIdx.x == 0) counts[blockIdx.x] = c;
    if ((int)threadIdx.x < (c < 64 ? c : 64))
        wl[blockIdx.x * 64 + threadIdx.x] = s_list[threadIdx.x];
}

// np-exact wave-per-point rescan (proven R7-R12).
__device__ __forceinline__ void refine_point(
    const float* __restrict__ x, const float* __restrict__ bnT,
    int* __restrict__ out, int n, int lane) {
#pragma clang fp contract(off)
    float a[K_DIM];
    norm_np(x, N_PTS, n, a);

    float best = -3.402823466e38f;
    int   idx  = 0x7fffffff;
    const float4* b4 = (const float4*)bnT;
    for (int t = 0; t < 16; ++t) {
        const int d = t * 64 + lane;
        const float4 q0 = b4[d * 4 + 0];
        const float4 q1 = b4[d * 4 + 1];
        const float4 q2 = b4[d * 4 + 2];
        const float4 q3 = b4[d * 4 + 3];
        float sc;
        sc = a[0] * q0.x;
        sc = sc + a[1]  * q0.y; sc = sc + a[2]  * q0.z; sc = sc + a[3]  * q0.w;
        sc = sc + a[4]  * q1.x; sc = sc + a[5]  * q1.y; sc = sc + a[6]  * q1.z;
        sc = sc + a[7]  * q1.w; sc = sc + a[8]  * q2.x; sc = sc + a[9]  * q2.y;
        sc = sc + a[10] * q2.z; sc = sc + a[11] * q2.w; sc = sc + a[12] * q3.x;
        sc = sc + a[13] * q3.y; sc = sc + a[14] * q3.z; sc = sc + a[15] * q3.w;
        if (sc > best) { best = sc; idx = d; }
    }
#pragma unroll
    for (int mk = 1; mk <= 32; mk <<= 1) {
        const float ob = __shfl_xor(best, mk);
        const int   oi = __shfl_xor(idx,  mk);
        if (ob > best || (ob == best && oi < idx)) { best = ob; idx = oi; }
    }
    if (lane == 0) out[n] = idx;
}

// Kernel 3: refine. 1024 blocks map 1:1 onto screen blocks/segments.
// count<=64: process the listed points. count>64 (overflow sentinel):
// rescan all 128 points of the block.
__global__ __launch_bounds__(256) void ncc_exact_refine(
    const float* __restrict__ x, const float* __restrict__ bnT,
    int* __restrict__ out, const int* __restrict__ wl,
    const int* __restrict__ counts) {
#pragma clang fp contract(off)
    const int b    = blockIdx.x;                    // grid = 1024
    const int lane = threadIdx.x & 63;
    const int wv   = threadIdx.x >> 6;              // 0..3
    const int c    = counts[b];

    if (c > 64) {
        for (int i = wv; i < 128; i += 4)
            refine_point(x, bnT, out, b * 128 + i, lane);
    } else {
        for (int i = wv; i < c; i += 4)
            refine_point(x, bnT, out, wl[b * 64 + i], lane);
    }
}

// Fallback (small ws): proven-exact full scan (R4).
__global__ __launch_bounds__(256) void ncc_argmax_np32(
    const float* __restrict__ x, const float* __restrict__ bnT,
    int* __restrict__ out) {
#pragma clang fp contract(off)
    const int n = blockIdx.x * 256 + threadIdx.x;
    float a[K_DIM];
    norm_np(x, N_PTS, n, a);

    float best = -3.402823466e38f;
    int   idx  = 0;
    const float4* b4 = (const float4*)bnT;
#pragma unroll 2
    for (int d = 0; d < D_BINS; ++d) {
        const float4 q0 = b4[d * 4 + 0];
        const float4 q1 = b4[d * 4 + 1];
        const float4 q2 = b4[d * 4 + 2];
        const float4 q3 = b4[d * 4 + 3];
        float sc;
        sc = a[0] * q0.x;
        sc = sc + a[1]  * q0.y; sc = sc + a[2]  * q0.z; sc = sc + a[3]  * q0.w;
        sc = sc + a[4]  * q1.x; sc = sc + a[5]  * q1.y; sc = sc + a[6]  * q1.z;
        sc = sc + a[7]  * q1.w; sc = sc + a[8]  * q2.x; sc = sc + a[9]  * q2.y;
        sc = sc + a[10] * q2.z; sc = sc + a[11] * q2.w; sc = sc + a[12] * q3.x;
        sc = sc + a[13] * q3.y; sc = sc + a[14] * q3.z; sc = sc + a[15] * q3.w;
        if (sc > best) { best = sc; idx = d; }
    }
    out[n] = idx;
}

__global__ __launch_bounds__(256) void normalize_rows_only(
    const float* __restrict__ cmat, float* __restrict__ bnT) {
#pragma clang fp contract(off)
    const int d = blockIdx.x * 256 + threadIdx.x;
    if (d >= D_BINS) return;
    float t[K_DIM];
    norm_np(cmat, D_BINS, d, t);
#pragma unroll
    for (int k = 0; k < K_DIM; ++k) bnT[d * K_DIM + k] = t[k];
}

extern "C" void kernel_launch(void* const* d_in, const int* in_sizes, int n_in,
                              void* d_out, int out_size, void* d_ws, size_t ws_size,
                              hipStream_t stream) {
    const float* x    = (const float*)d_in[0];   // [1, 16, 131072] fp32
    const float* cmat = (const float*)d_in[1];   // [16, 1024] fp32
    int* out = (int*)d_out;                      // [1, 131072] int32
    char* ws = (char*)d_ws;

    if (ws_size >= (size_t)WS_NEED) {
        int*            counts = (int*)(ws + WS_OFF_CNT);
        float*          bnT    = (float*)(ws + WS_OFF_BN);
        unsigned short* B1     = (unsigned short*)(ws + WS_OFF_B1);
        unsigned short* B2     = (unsigned short*)(ws + WS_OFF_B2);
        unsigned short* zblk   = (unsigned short*)(ws + WS_OFF_Z);
        int*            wl     = (int*)(ws + WS_OFF_WL);

        prep_b<<<4, 256, 0, stream>>>(cmat, bnT, B1, B2, zblk);
        mfma_screen<<<1024, 512, 0, stream>>>(
            x, (const uint4*)(ws + WS_OFF_B1), (const uint4*)(ws + WS_OFF_B2),
            out, wl, counts);
        ncc_exact_refine<<<1024, 256, 0, stream>>>(x, bnT, out, wl, counts);
    } else {
        float* bnT = (float*)(ws + WS_OFF_BN);
        normalize_rows_only<<<4, 256, 0, stream>>>(cmat, bnT);
        ncc_argmax_np32<<<512, 256, 0, stream>>>(x, bnT, out);
    }
}